// Round 21
// baseline (255.103 us; speedup 1.0000x reference)
//
#include <hip/hip_runtime.h>

#define N_NODES 100000
#define E_EDGES 3200000

// ---- bucket geometry ----
#define BSHIFT 7
#define BWIDTH 128                       // src values per bucket
#define NBUCKETS 782                     // ceil(100000/128)
#define BCAP 5120                        // fixed slots/bucket (mean 4096 +16s)
#define NB1 200                          // partition blocks (1024 thr each)
#define CHUNK1 16000                     // NB1*CHUNK1 == E_EDGES exactly

// Wct: transposed fused weight matrix, bf16, [80 cols][264 k-stride]
#define WCT_STRIDE 264
#define WCT_ELEMS (80 * WCT_STRIDE)      // 21120 ushorts

#define N_TILES (N_NODES / 16)           // 6250
#define ROW2_BLOCKS 192                  // 1024-thr row blocks (16 waves each)

// ---------------------------------------------------------------------------
// ws layout (float slots):
//   hem    [0,        3200000)   N*64 ushort bf16, PERMUTED: hem[d][r*4+n]
//   s8     [3200000,  4000000)   N*8 f32  [s_src+att_b (4) | s_dst (4)]
//   Wct    [4000000,  4010560)   21120 ushort
//   off8   [4010560,  4010568)   8 f32
//   rowptr [4010568,  4110568)   N ints (segment beg; end = beg + rowcnt)
//   rowcnt [4110568,  4210568)   N ints
//   gcur   [4210568,  4211368)   800 ints (per-bucket fill, memset 0)
//   sdq    [4211368,  4411368)   N*4 ushort bf16 dst-scores (0.8MB, L2-hot)
//   pairs  [4411368,  8415208)   NBUCKETS*BCAP ints (lsrc<<20 | dst)
//   sdst   [8415208, 12419048)   NBUCKETS*BCAP ints (dst sorted by src)
// total 49.7 MB (< 69.9 MB proven in R9)
// ---------------------------------------------------------------------------

typedef __attribute__((ext_vector_type(8))) short short8;
typedef __attribute__((ext_vector_type(4))) float f32x4;

__device__ __forceinline__ unsigned short f2bf(float f) {
    unsigned u = __float_as_uint(f);
    return (unsigned short)((u + 0x7FFFu + ((u >> 16) & 1u)) >> 16);  // RNE
}

// ===========================================================================
// K1: fuse_weights alone (tiny, ~10us) — unblocks row in K2.
// ===========================================================================
__global__ __launch_bounds__(256) void fuse_kernel(
    const float* __restrict__ W_lin, const float* __restrict__ b_lin,
    const float* __restrict__ att_w, const float* __restrict__ emb_w,
    unsigned short* __restrict__ Wct, float* __restrict__ off8) {
    const int wave = threadIdx.x >> 6, lane = threadIdx.x & 63;
    const int k = blockIdx.x * 4 + wave;  // 0..255
    float4 wv = *(const float4*)(W_lin + k * 256 + lane * 4);
    float acc[8];
#pragma unroll
    for (int j = 0; j < 8; ++j) {
        int l = j & 3, part = j >> 2;
        float4 av = *(const float4*)(att_w + l * 512 + part * 256 + lane * 4);
        acc[j] = wv.x * av.x + wv.y * av.y + wv.z * av.z + wv.w * av.w;
    }
#pragma unroll
    for (int j = 0; j < 8; ++j) {
        float v = acc[j];
#pragma unroll
        for (int off = 32; off >= 1; off >>= 1) v += __shfl_xor(v, off);
        acc[j] = v;
    }
    if (lane < 8) {  // static-index select
        float v = acc[0];
#pragma unroll
        for (int j = 1; j < 8; ++j) if (lane == j) v = acc[j];
        Wct[(64 + lane) * WCT_STRIDE + k] = f2bf(v);
    }
    Wct[lane * WCT_STRIDE + k] = f2bf(emb_w[k * 64 + lane]);  // transpose
    if (lane < 8) Wct[(72 + lane) * WCT_STRIDE + k] = 0;
    if (k < 8) {  // off8[k] = b_lin . a_row(k)
        int l = k & 3, part = k >> 2;
        float4 av = *(const float4*)(att_w + l * 512 + part * 256 + lane * 4);
        float4 bv = *(const float4*)(b_lin + lane * 4);
        float p = bv.x * av.x + bv.y * av.y + bv.z * av.z + bv.w * av.w;
#pragma unroll
        for (int off = 32; off >= 1; off >>= 1) p += __shfl_xor(p, off);
        if (lane == 0) off8[k] = p;
    }
}

// ===========================================================================
// K2 "partrow" (1024 threads): bpart (blocks 0..199) || row (blocks 200..391).
// Resource-complementary co-residency: per CU one bpart block (scatter
// latency-bound, 3KB LDS) + one row block (MFMA-bound, 42KB LDS) = 32 waves.
// Row at 16 waves/block also cuts Wl stagings 768 -> 192.
// ===========================================================================
__global__ __launch_bounds__(1024) void partrow_kernel(
    const int* __restrict__ src, const int* __restrict__ dst,
    int* __restrict__ gcur, int* __restrict__ pairs,
    const float* __restrict__ x, const unsigned short* __restrict__ Wct,
    const float* __restrict__ off8, const float* __restrict__ att_b,
    const float* __restrict__ emb_b,
    unsigned short* __restrict__ hem, float* __restrict__ s8,
    unsigned short* __restrict__ sdq) {
    __shared__ unsigned short Wl[WCT_ELEMS];  // 42.2 KB (row branch)
    int* h = (int*)Wl;                        // bpart branch alias (3.1 KB)
    if (blockIdx.x < NB1) {
        // ---- bpart: LDS hist -> global reservation -> scatter ----
        const int pb = blockIdx.x;
        for (int i = threadIdx.x; i < NBUCKETS; i += 1024) h[i] = 0;
        __syncthreads();
        const int base = pb * CHUNK1;
        for (int i = threadIdx.x; i < CHUNK1; i += 1024)
            atomicAdd(&h[src[base + i] >> BSHIFT], 1);
        __syncthreads();
        for (int b = threadIdx.x; b < NBUCKETS; b += 1024) {
            int c = h[b];
            h[b] = c ? atomicAdd(&gcur[b], c) : 0;  // reserve [h[b], h[b]+c)
        }
        __syncthreads();
        for (int i = threadIdx.x; i < CHUNK1; i += 1024) {
            int s = src[base + i];
            int b = s >> BSHIFT;
            int pos = atomicAdd(&h[b], 1);  // walks reserved range
            pairs[b * BCAP + pos] = ((s & (BWIDTH - 1)) << 20) | dst[base + i];
        }
    } else {
        // ---- row_mfma: 16 waves per block, wave-strided tiles ----
        const int rid = blockIdx.x - NB1;  // 0..191
        const int tid = threadIdx.x;
        for (int i = tid; i < WCT_ELEMS / 8; i += 1024)
            ((uint4*)Wl)[i] = ((const uint4*)Wct)[i];
        __syncthreads();
        const int wave = tid >> 6, lane = tid & 63;
        const int r = lane & 15, g = lane >> 4;
        const int gw = rid * 16 + wave, nw = ROW2_BLOCKS * 16;
        for (int tile = gw; tile < N_TILES; tile += nw) {
            const int row0 = tile * 16;
            const float* xr = x + (size_t)(row0 + r) * 256 + g * 8;
            f32x4 acc[5];
#pragma unroll
            for (int n = 0; n < 5; ++n) acc[n] = (f32x4){0.f, 0.f, 0.f, 0.f};
            for (int kk = 0; kk < 8; ++kk) {
                float4 xa = *(const float4*)(xr + kk * 32);
                float4 xb = *(const float4*)(xr + kk * 32 + 4);
                short8 a;
                a[0] = (short)f2bf(xa.x); a[1] = (short)f2bf(xa.y);
                a[2] = (short)f2bf(xa.z); a[3] = (short)f2bf(xa.w);
                a[4] = (short)f2bf(xb.x); a[5] = (short)f2bf(xb.y);
                a[6] = (short)f2bf(xb.z); a[7] = (short)f2bf(xb.w);
                const int bk = kk * 32 + g * 8;
#pragma unroll
                for (int n = 0; n < 5; ++n) {
                    short8 b = *(const short8*)(&Wl[(16 * n + r) * WCT_STRIDE + bk]);
                    acc[n] = __builtin_amdgcn_mfma_f32_16x16x32_bf16(a, b, acc[n],
                                                                     0, 0, 0);
                }
            }
#pragma unroll
            for (int q = 0; q < 4; ++q) {
                const int orow = row0 + g * 4 + q;
                unsigned e0 = f2bf(acc[0][q] + emb_b[r]);
                unsigned e1 = f2bf(acc[1][q] + emb_b[16 + r]);
                unsigned e2 = f2bf(acc[2][q] + emb_b[32 + r]);
                unsigned e3 = f2bf(acc[3][q] + emb_b[48 + r]);
                uint2 hv;
                hv.x = e0 | (e1 << 16);
                hv.y = e2 | (e3 << 16);
                *(uint2*)(hem + (size_t)orow * 64 + r * 4) = hv;  // permuted
                if (r < 8) {
                    const float sv =
                        acc[4][q] + off8[r] + (r < 4 ? att_b[r] : 0.f);
                    s8[(size_t)orow * 8 + r] = sv;
                    if (r >= 4)  // bf16 copy of dst-score: L2-hot gather array
                        sdq[(size_t)orow * 4 + (r - 4)] = f2bf(sv);
                }
            }
        }
    }
}

// ===========================================================================
// K3: per-bucket counting sort; emits rowptr (beg) + rowcnt + sorted dst.
// ===========================================================================
__global__ __launch_bounds__(256) void bsort_kernel(
    const int* __restrict__ gcur, const int* __restrict__ pairs,
    int* __restrict__ sdst, int* __restrict__ rowptr,
    int* __restrict__ rowcnt) {
    __shared__ int h[BWIDTH];
    const int b = blockIdx.x, t = threadIdx.x;
    const int beg = b * BCAP;
    const int end = beg + gcur[b];
    if (t < BWIDTH) h[t] = 0;
    __syncthreads();
    for (int i = beg + t; i < end; i += 256)
        atomicAdd(&h[pairs[i] >> 20], 1);
    __syncthreads();
    const int s0 = b << BSHIFT;
    if (t < BWIDTH && s0 + t < N_NODES) rowcnt[s0 + t] = h[t];
    __syncthreads();  // rowcnt reads h before the scan mutates it
    if (t == 0) {     // serial exclusive scan of 128 (cheap)
        int run = 0;
        for (int i = 0; i < BWIDTH; ++i) { int c = h[i]; h[i] = run; run += c; }
    }
    __syncthreads();
    if (t < BWIDTH && s0 + t < N_NODES) rowptr[s0 + t] = beg + h[t];
    __syncthreads();  // rowptr reads h before placement mutates it
    for (int i = beg + t; i < end; i += 256) {
        int p = pairs[i];
        int pos = beg + atomicAdd(&h[p >> 20], 1);
        sdst[pos] = p & 0xFFFFF;
    }
}

// ===========================================================================
// K4: node kernel — R11 structure + sdq gather + LDS LUT (byte-identical R20).
// ===========================================================================
template <int MASKED>
__device__ __forceinline__ void node_batch(
    const int* __restrict__ sdst, const unsigned short* __restrict__ sdq,
    const unsigned short* __restrict__ hem, const float2* lut,
    int base, int m, int g, unsigned ru4, int r3, float ssr,
    const short8& bones,
    f32x4& acc0, f32x4& acc1, f32x4& acc2, f32x4& acc3, f32x4& accd) {
    unsigned dj[8];
#pragma unroll
    for (int j = 0; j < 8; ++j) {
        int e = 4 * j + g;
        if (MASKED) e = min(e, m - 1);
        dj[j] = (unsigned)sdst[(unsigned)(base + e)];
    }
    unsigned short sq[8];
    uint2 hv[8];
#pragma unroll
    for (int j = 0; j < 8; ++j) {
        sq[j] = sdq[dj[j] * 4u + (unsigned)r3];
        hv[j] = *(const uint2*)(hem + dj[j] * 64u + ru4);
    }
    short8 a, b0, b1, b2, b3;
#pragma unroll
    for (int j = 0; j < 8; ++j) {
        const float sd = __uint_as_float((unsigned)sq[j] << 16);
        float t = ssr + sd;
        t = fminf(fmaxf(t, -8.0f), 7.96875f);
        const float u = (t + 8.0f) * 32.0f;     // [0, 511]
        const float fi = truncf(u);
        const float fr = u - fi;
        const float2 e = lut[(int)fi];
        float w = e.x + e.y * fr;
        if (MASKED) w = (4 * j + g < m) ? w : 0.f;
        a[j] = (short)(__float_as_uint(w) >> 16);  // truncated bf16
        b0[j] = (short)(hv[j].x & 0xFFFFu);
        b1[j] = (short)(hv[j].x >> 16);
        b2[j] = (short)(hv[j].y & 0xFFFFu);
        b3[j] = (short)(hv[j].y >> 16);
    }
    acc0 = __builtin_amdgcn_mfma_f32_16x16x32_bf16(a, b0, acc0, 0, 0, 0);
    acc1 = __builtin_amdgcn_mfma_f32_16x16x32_bf16(a, b1, acc1, 0, 0, 0);
    acc2 = __builtin_amdgcn_mfma_f32_16x16x32_bf16(a, b2, acc2, 0, 0, 0);
    acc3 = __builtin_amdgcn_mfma_f32_16x16x32_bf16(a, b3, acc3, 0, 0, 0);
    accd = __builtin_amdgcn_mfma_f32_16x16x32_bf16(a, bones, accd, 0, 0, 0);
}

__global__ __launch_bounds__(256) void node_kernel(
    const int* __restrict__ rowptr, const int* __restrict__ rowcnt,
    const int* __restrict__ sdst, const float* __restrict__ s8,
    const unsigned short* __restrict__ sdq,
    const unsigned short* __restrict__ hem, float* __restrict__ out) {
    __shared__ float2 lut[512];
    for (int i = threadIdx.x; i < 512; i += 256) {
        const float t0 = -8.0f + i * (1.0f / 32.0f);
        const float t1 = t0 + (1.0f / 32.0f);
        const float w0 = __expf(1.0f / (1.0f + __expf(-t0)));
        const float w1 = __expf(1.0f / (1.0f + __expf(-t1)));
        lut[i] = make_float2(w0, w1 - w0);
    }
    __syncthreads();
    const int lane = threadIdx.x & 63;
    const int r = lane & 15, g = lane >> 4, r3 = r & 3;
    const unsigned ru4 = (unsigned)(r * 4);
    const short8 bones = {16256, 16256, 16256, 16256,
                          16256, 16256, 16256, 16256};  // bf16 1.0 x8
    const int gw = (blockIdx.x * blockDim.x + threadIdx.x) >> 6;
    const int nw = (gridDim.x * blockDim.x) >> 6;
    for (int s = gw; s < N_NODES; s += nw) {
        const int beg = rowptr[s];
        const int deg = rowcnt[s];
        const float ssr = s8[(unsigned)s * 8u + (unsigned)r3];  // +att_b
        f32x4 a0 = {0.f, 0.f, 0.f, 0.f}, a1 = {0.f, 0.f, 0.f, 0.f};
        f32x4 a2 = {0.f, 0.f, 0.f, 0.f}, a3 = {0.f, 0.f, 0.f, 0.f};
        f32x4 ad = {0.f, 0.f, 0.f, 0.f};
        const int nfull = deg >> 5;
        int base = beg;
        for (int f = 0; f < nfull; ++f, base += 32)
            node_batch<0>(sdst, sdq, hem, lut, base, 32, g, ru4, r3, ssr,
                          bones, a0, a1, a2, a3, ad);
        const int m = deg - (base - beg);
        if (m > 0)
            node_batch<1>(sdst, sdq, hem, lut, base, m, g, ru4, r3, ssr,
                          bones, a0, a1, a2, a3, ad);
        const float i0 = ad[0] > 0.f ? 1.f / ad[0] : 0.f;
        const float i1 = ad[1] > 0.f ? 1.f / ad[1] : 0.f;
        const float i2 = ad[2] > 0.f ? 1.f / ad[2] : 0.f;
        const float i3 = ad[3] > 0.f ? 1.f / ad[3] : 0.f;
        f32x4 av = a0;                   // g-group selects its column tile
        if (g == 1) av = a1;
        if (g == 2) av = a2;
        if (g == 3) av = a3;
        float* o = out + (size_t)s * 256 + g * 16 + r;
        o[0]   = av[0] * i0;
        o[64]  = av[1] * i1;
        o[128] = av[2] * i2;
        o[192] = av[3] * i3;
    }
}

extern "C" void kernel_launch(void* const* d_in, const int* in_sizes, int n_in,
                              void* d_out, int out_size, void* d_ws, size_t ws_size,
                              hipStream_t stream) {
    const float* x     = (const float*)d_in[0];
    const int*   src   = (const int*)d_in[1];
    const int*   dst   = (const int*)d_in[2];
    const float* W_lin = (const float*)d_in[3];
    const float* b_lin = (const float*)d_in[4];
    const float* att_w = (const float*)d_in[5];
    const float* att_b = (const float*)d_in[6];
    const float* emb_w = (const float*)d_in[7];
    const float* emb_b = (const float*)d_in[8];
    float* out = (float*)d_out;
    float* ws  = (float*)d_ws;

    unsigned short* hem = (unsigned short*)ws;
    float* s8     = ws + 3200000;
    unsigned short* Wct = (unsigned short*)(ws + 4000000);
    float* off8   = ws + 4010560;
    int*   rowptr = (int*)(ws + 4010568);
    int*   rowcnt = (int*)(ws + 4110568);
    int*   gcur   = (int*)(ws + 4210568);
    unsigned short* sdq = (unsigned short*)(ws + 4211368);
    int*   pairs  = (int*)(ws + 4411368);
    int*   sdst   = (int*)(ws + 8415208);

    hipMemsetAsync(gcur, 0, 800 * sizeof(int), stream);

    fuse_kernel<<<64, 256, 0, stream>>>(W_lin, b_lin, att_w, emb_w, Wct, off8);
    partrow_kernel<<<NB1 + ROW2_BLOCKS, 1024, 0, stream>>>(
        src, dst, gcur, pairs, x, Wct, off8, att_b, emb_b, hem, s8, sdq);
    bsort_kernel<<<NBUCKETS, 256, 0, stream>>>(gcur, pairs, sdst, rowptr,
                                               rowcnt);
    node_kernel<<<4096, 256, 0, stream>>>(rowptr, rowcnt, sdst, s8, sdq, hem,
                                          out);
}

// Round 22
// 197.726 us; speedup vs baseline: 1.2902x; 1.2902x over previous
//
#include <hip/hip_runtime.h>

#define N_NODES 100000
#define E_EDGES 3200000

// ---- bucket geometry ----
#define BSHIFT 7
#define BWIDTH 128                       // src values per bucket
#define NBUCKETS 782                     // ceil(100000/128)
#define BCAP 5120                        // fixed slots/bucket (mean 4096 +16s)
#define NB1 200                          // partition blocks (1024 thr each)
#define CHUNK1 16000                     // NB1*CHUNK1 == E_EDGES exactly

// Wct: transposed fused weight matrix, bf16, [80 cols][264 k-stride]
#define WCT_STRIDE 264
#define WCT_ELEMS (80 * WCT_STRIDE)      // 21120 ushorts

#define N_TILES (N_NODES / 16)           // 6250
#define ROW_BLOCKS 768                   // 3 per CU (LDS-limited)

// ---------------------------------------------------------------------------
// ws layout (float slots):
//   hem    [0,        3200000)   N*64 ushort bf16, PERMUTED: hem[d][r*4+n]
//   s8     [3200000,  4000000)   N*8 f32  [s_src+att_b (4) | s_dst (4)]
//   Wct    [4000000,  4010560)   21120 ushort
//   off8   [4010560,  4010568)   8 f32
//   rowptr [4010568,  4110568)   N ints (segment beg; end = beg + rowcnt)
//   rowcnt [4110568,  4210568)   N ints
//   gcur   [4210568,  4211368)   800 ints (per-bucket fill, memset 0)
//   sdq    [4211368,  4411368)   N*4 ushort bf16 dst-scores (0.8MB, L2-hot)
//   pairs  [4411368,  8415208)   NBUCKETS*BCAP ints (lsrc<<20 | dst)
//   sdst   [8415208, 12419048)   NBUCKETS*BCAP ints (dst sorted by src)
// total 49.7 MB (< 69.9 MB proven in R9)
// ---------------------------------------------------------------------------

typedef __attribute__((ext_vector_type(8))) short short8;
typedef __attribute__((ext_vector_type(4))) float f32x4;

__device__ __forceinline__ unsigned short f2bf(float f) {
    unsigned u = __float_as_uint(f);
    return (unsigned short)((u + 0x7FFFu + ((u >> 16) & 1u)) >> 16);  // RNE
}

// ===========================================================================
// K1 "prep" (1024 threads): fuse_weights (blocks 0..63, first 256 threads)
//                        || bpart (blocks 64..263, full 1024 threads).
// ===========================================================================
__global__ __launch_bounds__(1024) void prep_kernel(
    const float* __restrict__ W_lin, const float* __restrict__ b_lin,
    const float* __restrict__ att_w, const float* __restrict__ emb_w,
    unsigned short* __restrict__ Wct, float* __restrict__ off8,
    const int* __restrict__ src, const int* __restrict__ dst,
    int* __restrict__ gcur, int* __restrict__ pairs) {
    __shared__ int h[NBUCKETS];
    if (blockIdx.x < 64) {
        // ---- fuse_weights: one wave per k (k = bid*4 + wave), tid<256 ----
        if (threadIdx.x >= 256) return;
        const int wave = threadIdx.x >> 6, lane = threadIdx.x & 63;
        const int k = blockIdx.x * 4 + wave;  // 0..255
        float4 wv = *(const float4*)(W_lin + k * 256 + lane * 4);
        float acc[8];
#pragma unroll
        for (int j = 0; j < 8; ++j) {
            int l = j & 3, part = j >> 2;
            float4 av = *(const float4*)(att_w + l * 512 + part * 256 + lane * 4);
            acc[j] = wv.x * av.x + wv.y * av.y + wv.z * av.z + wv.w * av.w;
        }
#pragma unroll
        for (int j = 0; j < 8; ++j) {
            float v = acc[j];
#pragma unroll
            for (int off = 32; off >= 1; off >>= 1) v += __shfl_xor(v, off);
            acc[j] = v;
        }
        if (lane < 8) {  // static-index select
            float v = acc[0];
#pragma unroll
            for (int j = 1; j < 8; ++j) if (lane == j) v = acc[j];
            Wct[(64 + lane) * WCT_STRIDE + k] = f2bf(v);
        }
        Wct[lane * WCT_STRIDE + k] = f2bf(emb_w[k * 64 + lane]);  // transpose
        if (lane < 8) Wct[(72 + lane) * WCT_STRIDE + k] = 0;
        if (k < 8) {  // off8[k] = b_lin . a_row(k)
            int l = k & 3, part = k >> 2;
            float4 av = *(const float4*)(att_w + l * 512 + part * 256 + lane * 4);
            float4 bv = *(const float4*)(b_lin + lane * 4);
            float p = bv.x * av.x + bv.y * av.y + bv.z * av.z + bv.w * av.w;
#pragma unroll
            for (int off = 32; off >= 1; off >>= 1) p += __shfl_xor(p, off);
            if (lane == 0) off8[k] = p;
        }
    } else {
        // ---- bpart: LDS hist -> global reservation -> scatter ----
        const int pb = blockIdx.x - 64;  // 0..NB1-1
        for (int i = threadIdx.x; i < NBUCKETS; i += 1024) h[i] = 0;
        __syncthreads();
        const int base = pb * CHUNK1;
        for (int i = threadIdx.x; i < CHUNK1; i += 1024)
            atomicAdd(&h[src[base + i] >> BSHIFT], 1);
        __syncthreads();
        for (int b = threadIdx.x; b < NBUCKETS; b += 1024) {
            int c = h[b];
            h[b] = c ? atomicAdd(&gcur[b], c) : 0;  // reserve [h[b], h[b]+c)
        }
        __syncthreads();
        for (int i = threadIdx.x; i < CHUNK1; i += 1024) {
            int s = src[base + i];
            int b = s >> BSHIFT;
            int pos = atomicAdd(&h[b], 1);  // walks reserved range
            pairs[b * BCAP + pos] = ((s & (BWIDTH - 1)) << 20) | dst[base + i];
        }
    }
}

// ===========================================================================
// K2 "mid": row_mfma  ||  bsort, block-interleaved (even->row, odd->bsort).
// bsort's 512B hist aliases the head of row's 42KB Wl (different blocks).
// ===========================================================================
__global__ __launch_bounds__(256) void mid_kernel(
    const float* __restrict__ x, const unsigned short* __restrict__ Wct,
    const float* __restrict__ off8, const float* __restrict__ att_b,
    const float* __restrict__ emb_b,
    unsigned short* __restrict__ hem, float* __restrict__ s8,
    unsigned short* __restrict__ sdq,
    const int* __restrict__ gcur, const int* __restrict__ pairs,
    int* __restrict__ sdst, int* __restrict__ rowptr,
    int* __restrict__ rowcnt) {
    __shared__ unsigned short Wl[WCT_ELEMS];  // 42.2 KB (row branch)
    int* h = (int*)Wl;                        // bsort branch alias (512 B)
    const int bid = blockIdx.x;
    const bool is_row = (bid < 2 * ROW_BLOCKS) && ((bid & 1) == 0);
    if (is_row) {
        const int rid = bid >> 1;  // 0..767
        const int tid = threadIdx.x;
        for (int i = tid; i < WCT_ELEMS / 8; i += 256)
            ((uint4*)Wl)[i] = ((const uint4*)Wct)[i];
        __syncthreads();
        const int wave = tid >> 6, lane = tid & 63;
        const int r = lane & 15, g = lane >> 4;
        const int gw = rid * 4 + wave, nw = ROW_BLOCKS * 4;
        for (int tile = gw; tile < N_TILES; tile += nw) {
            const int row0 = tile * 16;
            const float* xr = x + (size_t)(row0 + r) * 256 + g * 8;
            f32x4 acc[5];
#pragma unroll
            for (int n = 0; n < 5; ++n) acc[n] = (f32x4){0.f, 0.f, 0.f, 0.f};
            for (int kk = 0; kk < 8; ++kk) {
                float4 xa = *(const float4*)(xr + kk * 32);
                float4 xb = *(const float4*)(xr + kk * 32 + 4);
                short8 a;
                a[0] = (short)f2bf(xa.x); a[1] = (short)f2bf(xa.y);
                a[2] = (short)f2bf(xa.z); a[3] = (short)f2bf(xa.w);
                a[4] = (short)f2bf(xb.x); a[5] = (short)f2bf(xb.y);
                a[6] = (short)f2bf(xb.z); a[7] = (short)f2bf(xb.w);
                const int bk = kk * 32 + g * 8;
#pragma unroll
                for (int n = 0; n < 5; ++n) {
                    short8 b = *(const short8*)(&Wl[(16 * n + r) * WCT_STRIDE + bk]);
                    acc[n] = __builtin_amdgcn_mfma_f32_16x16x32_bf16(a, b, acc[n],
                                                                     0, 0, 0);
                }
            }
#pragma unroll
            for (int q = 0; q < 4; ++q) {
                const int orow = row0 + g * 4 + q;
                unsigned e0 = f2bf(acc[0][q] + emb_b[r]);
                unsigned e1 = f2bf(acc[1][q] + emb_b[16 + r]);
                unsigned e2 = f2bf(acc[2][q] + emb_b[32 + r]);
                unsigned e3 = f2bf(acc[3][q] + emb_b[48 + r]);
                uint2 hv;
                hv.x = e0 | (e1 << 16);
                hv.y = e2 | (e3 << 16);
                *(uint2*)(hem + (size_t)orow * 64 + r * 4) = hv;  // permuted
                if (r < 8) {
                    const float sv =
                        acc[4][q] + off8[r] + (r < 4 ? att_b[r] : 0.f);
                    s8[(size_t)orow * 8 + r] = sv;
                    if (r >= 4)  // bf16 copy of dst-score: L2-hot gather array
                        sdq[(size_t)orow * 4 + (r - 4)] = f2bf(sv);
                }
            }
        }
    } else {
        const int b = (bid < 2 * ROW_BLOCKS) ? (bid >> 1)
                                             : (ROW_BLOCKS + bid - 2 * ROW_BLOCKS);
        const int t = threadIdx.x;
        const int beg = b * BCAP;
        const int end = beg + gcur[b];
        if (t < BWIDTH) h[t] = 0;
        __syncthreads();
        for (int i = beg + t; i < end; i += 256)
            atomicAdd(&h[pairs[i] >> 20], 1);
        __syncthreads();
        const int s0 = b << BSHIFT;
        if (t < BWIDTH && s0 + t < N_NODES) rowcnt[s0 + t] = h[t];
        __syncthreads();  // rowcnt reads h before the scan mutates it
        if (t == 0) {     // serial exclusive scan of 128 (cheap)
            int run = 0;
            for (int i = 0; i < BWIDTH; ++i) { int c = h[i]; h[i] = run; run += c; }
        }
        __syncthreads();
        if (t < BWIDTH && s0 + t < N_NODES) rowptr[s0 + t] = beg + h[t];
        __syncthreads();  // rowptr reads h before placement mutates it
        for (int i = beg + t; i < end; i += 256) {
            int p = pairs[i];
            int pos = beg + atomicAdd(&h[p >> 20], 1);
            sdst[pos] = p & 0xFFFFF;
        }
    }
}

// ===========================================================================
// node kernel — R11 structure + sdq gather + LDS LUT for w(t)=exp(sigmoid(t)).
// LUT: 512 x (base, slope) over t in [-8, 8), step 1/32; linear interp.
// ===========================================================================
template <int MASKED>
__device__ __forceinline__ void node_batch(
    const int* __restrict__ sdst, const unsigned short* __restrict__ sdq,
    const unsigned short* __restrict__ hem, const float2* lut,
    int base, int m, int g, unsigned ru4, int r3, float ssr,
    const short8& bones,
    f32x4& acc0, f32x4& acc1, f32x4& acc2, f32x4& acc3, f32x4& accd) {
    unsigned dj[8];
#pragma unroll
    for (int j = 0; j < 8; ++j) {
        int e = 4 * j + g;
        if (MASKED) e = min(e, m - 1);
        dj[j] = (unsigned)sdst[(unsigned)(base + e)];
    }
    unsigned short sq[8];
    uint2 hv[8];
#pragma unroll
    for (int j = 0; j < 8; ++j) {
        sq[j] = sdq[dj[j] * 4u + (unsigned)r3];
        hv[j] = *(const uint2*)(hem + dj[j] * 64u + ru4);
    }
    short8 a, b0, b1, b2, b3;
#pragma unroll
    for (int j = 0; j < 8; ++j) {
        const float sd = __uint_as_float((unsigned)sq[j] << 16);
        float t = ssr + sd;
        t = fminf(fmaxf(t, -8.0f), 7.96875f);
        const float u = (t + 8.0f) * 32.0f;     // [0, 511]
        const float fi = truncf(u);
        const float fr = u - fi;
        const float2 e = lut[(int)fi];
        float w = e.x + e.y * fr;
        if (MASKED) w = (4 * j + g < m) ? w : 0.f;
        a[j] = (short)(__float_as_uint(w) >> 16);  // truncated bf16
        b0[j] = (short)(hv[j].x & 0xFFFFu);
        b1[j] = (short)(hv[j].x >> 16);
        b2[j] = (short)(hv[j].y & 0xFFFFu);
        b3[j] = (short)(hv[j].y >> 16);
    }
    acc0 = __builtin_amdgcn_mfma_f32_16x16x32_bf16(a, b0, acc0, 0, 0, 0);
    acc1 = __builtin_amdgcn_mfma_f32_16x16x32_bf16(a, b1, acc1, 0, 0, 0);
    acc2 = __builtin_amdgcn_mfma_f32_16x16x32_bf16(a, b2, acc2, 0, 0, 0);
    acc3 = __builtin_amdgcn_mfma_f32_16x16x32_bf16(a, b3, acc3, 0, 0, 0);
    accd = __builtin_amdgcn_mfma_f32_16x16x32_bf16(a, bones, accd, 0, 0, 0);
}

__global__ __launch_bounds__(256) void node_kernel(
    const int* __restrict__ rowptr, const int* __restrict__ rowcnt,
    const int* __restrict__ sdst, const float* __restrict__ s8,
    const unsigned short* __restrict__ sdq,
    const unsigned short* __restrict__ hem, float* __restrict__ out) {
    __shared__ float2 lut[512];
    for (int i = threadIdx.x; i < 512; i += 256) {
        const float t0 = -8.0f + i * (1.0f / 32.0f);
        const float t1 = t0 + (1.0f / 32.0f);
        const float w0 = __expf(1.0f / (1.0f + __expf(-t0)));
        const float w1 = __expf(1.0f / (1.0f + __expf(-t1)));
        lut[i] = make_float2(w0, w1 - w0);
    }
    __syncthreads();
    const int lane = threadIdx.x & 63;
    const int r = lane & 15, g = lane >> 4, r3 = r & 3;
    const unsigned ru4 = (unsigned)(r * 4);
    const short8 bones = {16256, 16256, 16256, 16256,
                          16256, 16256, 16256, 16256};  // bf16 1.0 x8
    const int gw = (blockIdx.x * blockDim.x + threadIdx.x) >> 6;
    const int nw = (gridDim.x * blockDim.x) >> 6;
    for (int s = gw; s < N_NODES; s += nw) {
        const int beg = rowptr[s];
        const int deg = rowcnt[s];
        const float ssr = s8[(unsigned)s * 8u + (unsigned)r3];  // +att_b
        f32x4 a0 = {0.f, 0.f, 0.f, 0.f}, a1 = {0.f, 0.f, 0.f, 0.f};
        f32x4 a2 = {0.f, 0.f, 0.f, 0.f}, a3 = {0.f, 0.f, 0.f, 0.f};
        f32x4 ad = {0.f, 0.f, 0.f, 0.f};
        const int nfull = deg >> 5;
        int base = beg;
        for (int f = 0; f < nfull; ++f, base += 32)
            node_batch<0>(sdst, sdq, hem, lut, base, 32, g, ru4, r3, ssr,
                          bones, a0, a1, a2, a3, ad);
        const int m = deg - (base - beg);
        if (m > 0)
            node_batch<1>(sdst, sdq, hem, lut, base, m, g, ru4, r3, ssr,
                          bones, a0, a1, a2, a3, ad);
        const float i0 = ad[0] > 0.f ? 1.f / ad[0] : 0.f;
        const float i1 = ad[1] > 0.f ? 1.f / ad[1] : 0.f;
        const float i2 = ad[2] > 0.f ? 1.f / ad[2] : 0.f;
        const float i3 = ad[3] > 0.f ? 1.f / ad[3] : 0.f;
        f32x4 av = a0;                   // g-group selects its column tile
        if (g == 1) av = a1;
        if (g == 2) av = a2;
        if (g == 3) av = a3;
        float* o = out + (size_t)s * 256 + g * 16 + r;
        o[0]   = av[0] * i0;
        o[64]  = av[1] * i1;
        o[128] = av[2] * i2;
        o[192] = av[3] * i3;
    }
}

extern "C" void kernel_launch(void* const* d_in, const int* in_sizes, int n_in,
                              void* d_out, int out_size, void* d_ws, size_t ws_size,
                              hipStream_t stream) {
    const float* x     = (const float*)d_in[0];
    const int*   src   = (const int*)d_in[1];
    const int*   dst   = (const int*)d_in[2];
    const float* W_lin = (const float*)d_in[3];
    const float* b_lin = (const float*)d_in[4];
    const float* att_w = (const float*)d_in[5];
    const float* att_b = (const float*)d_in[6];
    const float* emb_w = (const float*)d_in[7];
    const float* emb_b = (const float*)d_in[8];
    float* out = (float*)d_out;
    float* ws  = (float*)d_ws;

    unsigned short* hem = (unsigned short*)ws;
    float* s8     = ws + 3200000;
    unsigned short* Wct = (unsigned short*)(ws + 4000000);
    float* off8   = ws + 4010560;
    int*   rowptr = (int*)(ws + 4010568);
    int*   rowcnt = (int*)(ws + 4110568);
    int*   gcur   = (int*)(ws + 4210568);
    unsigned short* sdq = (unsigned short*)(ws + 4211368);
    int*   pairs  = (int*)(ws + 4411368);
    int*   sdst   = (int*)(ws + 8415208);

    hipMemsetAsync(gcur, 0, 800 * sizeof(int), stream);

    prep_kernel<<<64 + NB1, 1024, 0, stream>>>(W_lin, b_lin, att_w, emb_w,
                                               Wct, off8, src, dst, gcur,
                                               pairs);
    mid_kernel<<<2 * ROW_BLOCKS + (NBUCKETS - ROW_BLOCKS), 256, 0, stream>>>(
        x, Wct, off8, att_b, emb_b, hem, s8, sdq, gcur, pairs, sdst, rowptr,
        rowcnt);
    node_kernel<<<4096, 256, 0, stream>>>(rowptr, rowcnt, sdst, s8, sdq, hem,
                                          out);
}